// Round 6
// baseline (1047.704 us; speedup 1.0000x reference)
//
#include <hip/hip_runtime.h>
#include <hip/hip_fp16.h>

typedef _Float16 f16;
typedef __attribute__((ext_vector_type(8))) _Float16 f16x8;
typedef __attribute__((ext_vector_type(4))) float f32x4;

#define MFMA16 __builtin_amdgcn_mfma_f32_16x16x32_f16
#define BAR() __builtin_amdgcn_s_barrier()
#define VMCNT(n) asm volatile("s_waitcnt vmcnt(" #n ")" ::: "memory")
#define LGKM(n) asm volatile("s_waitcnt lgkmcnt(" #n ")" ::: "memory")
#define SCHEDB() __builtin_amdgcn_sched_barrier(0)

__device__ __forceinline__ void gload16(const f16* g, char* l) {
  __builtin_amdgcn_global_load_lds(
      (const __attribute__((address_space(1))) void*)g,
      (__attribute__((address_space(3))) void*)l, 16, 0, 0);
}

// ---------------- fp32 -> fp16 bulk convert (nt loads: one-shot stream) ----------
__global__ __launch_bounds__(256) void cvt_k(const float* __restrict__ in,
                                             f16* __restrict__ out, int n8) {
  int i = blockIdx.x * 256 + threadIdx.x;
  const int stride = gridDim.x * 256;
  for (; i < n8; i += stride) {
    const f32x4* p = (const f32x4*)(in + (size_t)i * 8);
    f32x4 a = __builtin_nontemporal_load(p);
    f32x4 b = __builtin_nontemporal_load(p + 1);
    f16x8 h;
    h[0] = (f16)a[0]; h[1] = (f16)a[1]; h[2] = (f16)a[2]; h[3] = (f16)a[3];
    h[4] = (f16)b[0]; h[5] = (f16)b[1]; h[6] = (f16)b[2]; h[7] = (f16)b[3];
    *(f16x8*)(out + (size_t)i * 8) = h;  // normal: re-read by gemm soon
  }
}

// ---------------- rpb gather ----------------
__global__ __launch_bounds__(256) void rpb_build_k(const float* __restrict__ tab,
                                                   const int* __restrict__ rel,
                                                   f16* __restrict__ out) {
  int i = blockIdx.x * 256 + threadIdx.x;
  if (i >= 196 * 196) return;
  int idx = __builtin_nontemporal_load(rel + i);
#pragma unroll
  for (int h = 0; h < 12; ++h)
    out[h * (196 * 196) + i] = (f16)tab[idx * 12 + h];
}

// ---------------- 256x256 2-phase GEMM: C = A[M,768] @ W[N,768]^T ----------------
// 512 thr / 8 waves (2Mx4N), BK=64, LDS 128KB dbuf, swizzled chunks.
// Epilogue output streams use NON-TEMPORAL stores (not re-read before eviction;
// keeps A/B panels resident in L2 -> stage loads hit L2, vmcnt stall shrinks).
template <int MODE>
__global__ __launch_bounds__(512) void gemm_k(
    const f16* __restrict__ A, const f16* __restrict__ W,
    const float* __restrict__ bias_a, const float* __restrict__ bias_b,
    f16* __restrict__ q_out, f16* __restrict__ k_out, f16* __restrict__ vT_out,
    float* __restrict__ f_out) {
  constexpr int NTIL = (MODE == 0) ? 9 : 3;     // 2304/256 or 768/256
  constexpr int NWG = 196 * NTIL;
  constexpr int QX = NWG / 8, RX = NWG % 8;
  constexpr int KT = 12;                        // 768/64

  extern __shared__ char lds[];  // [2 buf][A 32K | B 32K]; row = 64 f16 = 128B

  const int tid = threadIdx.x;
  const int lane = tid & 63, wid = tid >> 6;
  const int xcd = blockIdx.x & 7, bix = blockIdx.x >> 3;
  const int lbid =
      (xcd < RX ? xcd * (QX + 1) : RX * (QX + 1) + (xcd - RX) * QX) + bix;
  const int brow = lbid / NTIL, bcol = lbid % NTIL;
  const int wr = wid >> 2, wc = wid & 3;
  const int l15 = lane & 15, g4 = lane >> 4;

  // staging: thread covers row sr of each 64-row quarter; pre-swizzled k-chunk
  const int sr = wid * 8 + (lane >> 3);
  const int scw = ((lane & 7) ^ (lane >> 3)) * 8;
  const f16* pAt = A + (size_t)(brow * 256 + sr) * 768 + scw;
  const f16* pBt = W + (size_t)(bcol * 256 + sr) * 768 + scw;
  char* ldsW = lds + wid * 1024;  // wave-uniform; HW adds lane*16

  auto stA = [&](int kt, int hf, int buf) {
#pragma unroll
    for (int i = 0; i < 2; ++i)
      gload16(pAt + (size_t)(hf * 128 + i * 64) * 768 + kt * 64,
              ldsW + buf * 65536 + hf * 16384 + i * 8192);
  };
  auto stB = [&](int kt, int hf, int buf) {
#pragma unroll
    for (int i = 0; i < 2; ++i)
      gload16(pBt + (size_t)(hf * 128 + i * 64) * 768 + kt * 64,
              ldsW + buf * 65536 + 32768 + hf * 16384 + i * 8192);
  };

  f16x8 af[2][4][2], bf[2][2][2];
  const int aswz = l15 & 7;
  const char* ldsAl = lds + (size_t)(wr * 128 + l15) * 128;
  const char* ldsBl = lds + 32768 + (size_t)(wc * 64 + l15) * 128;

  auto rdA = [&](int q, int buf) {
#pragma unroll
    for (int mf = 0; mf < 4; ++mf)
#pragma unroll
      for (int ks = 0; ks < 2; ++ks)
        af[q][mf][ks] = *(const f16x8*)(ldsAl + buf * 65536 +
                                        (q * 64 + mf * 16) * 128 +
                                        ((ks * 4 + g4) ^ aswz) * 16);
  };
  auto rdB = [&](int r, int buf) {
#pragma unroll
    for (int nf = 0; nf < 2; ++nf)
#pragma unroll
      for (int ks = 0; ks < 2; ++ks)
        bf[r][nf][ks] = *(const f16x8*)(ldsBl + buf * 65536 +
                                        (r * 32 + nf * 16) * 128 +
                                        ((ks * 4 + g4) ^ aswz) * 16);
  };

  const f32x4 zero4 = {0.f, 0.f, 0.f, 0.f};
  f32x4 acc[8][4];
#pragma unroll
  for (int i = 0; i < 8; ++i)
#pragma unroll
    for (int j = 0; j < 4; ++j) acc[i][j] = zero4;

  auto mm = [&](int q, int r) {
#pragma unroll
    for (int ks = 0; ks < 2; ++ks)
#pragma unroll
      for (int mf = 0; mf < 4; ++mf)
#pragma unroll
        for (int nf = 0; nf < 2; ++nf)
          acc[q * 4 + mf][r * 2 + nf] =
              MFMA16(af[q][mf][ks], bf[r][nf][ks], acc[q * 4 + mf][r * 2 + nf],
                     0, 0, 0);
  };

  // prologue: stage tile 0
  stA(0, 0, 0); stA(0, 1, 0); stB(0, 0, 0); stB(0, 1, 0);
  VMCNT(0);
  BAR();

  for (int t = 0; t < KT; ++t) {
    const int cur = t & 1, nxt = cur ^ 1;
    if (t + 1 < KT) {
      stA(t + 1, 0, nxt); stA(t + 1, 1, nxt);
      stB(t + 1, 0, nxt); stB(t + 1, 1, nxt);
    }
    rdA(0, cur); rdB(0, cur);
    SCHEDB();
    rdA(1, cur); rdB(1, cur);
    LGKM(12);
    SCHEDB();
    __builtin_amdgcn_s_setprio(1); mm(0, 0); mm(0, 1); __builtin_amdgcn_s_setprio(0);
    LGKM(0);
    SCHEDB();
    __builtin_amdgcn_s_setprio(1); mm(1, 0); mm(1, 1); __builtin_amdgcn_s_setprio(0);
    VMCNT(0);
    BAR();
  }

  // ---- epilogue (non-temporal output streams) ----
#pragma unroll
  for (int mf = 0; mf < 8; ++mf) {
    const int rowo = wr * 128 + (mf >> 2) * 64 + (mf & 3) * 16 + g4 * 4;
#pragma unroll
    for (int rr = 0; rr < 4; ++rr) {
      const int grow = brow * 256 + rowo + rr;
      if constexpr (MODE == 0) {
        const int bI = grow / 196;
        const int nI = grow - bI * 196;
#pragma unroll
        for (int nf = 0; nf < 4; ++nf) {
          const int col = bcol * 256 + wc * 64 + (nf >> 1) * 32 + (nf & 1) * 16 + l15;
          const int s = bcol / 3;
          const int rem = col - s * 768;
          const int hh = rem >> 6, dd = rem & 63;
          float v = acc[mf][nf][rr];
          if (s == 0) {
            v = (v + bias_a[rem]) * 0.125f;
            __builtin_nontemporal_store(
                (f16)v, &q_out[(((size_t)bI * 12 + hh) * 196 + nI) * 64 + dd]);
          } else if (s == 1) {
            __builtin_nontemporal_store(
                (f16)v, &k_out[(((size_t)bI * 12 + hh) * 196 + nI) * 64 + dd]);
          } else {
            v += bias_b[rem];
            __builtin_nontemporal_store(
                (f16)v, &vT_out[(((size_t)bI * 12 + hh) * 64 + dd) * 224 + nI]);
          }
        }
      } else {
        float* orow = f_out + (size_t)grow * 768;
#pragma unroll
        for (int nf = 0; nf < 4; ++nf) {
          const int col = bcol * 256 + wc * 64 + (nf >> 1) * 32 + (nf & 1) * 16 + l15;
          __builtin_nontemporal_store(acc[mf][nf][rr] + bias_a[col], &orow[col]);
        }
      }
    }
  }
}

// ---------------- fused window attention: one WG (4 waves) per (b,h) -------------
// V + P in LDS (64KB -> 2 blocks/CU); K, Q, rpb direct from global.
__global__ __launch_bounds__(256) void attn_k(const f16* __restrict__ qg,
                                              const f16* __restrict__ kg,
                                              const f16* __restrict__ vTg,
                                              const f16* __restrict__ rpb,
                                              f16* __restrict__ og) {
  extern __shared__ char smem[];
  f16x8* Vlds = (f16x8*)smem;              // [64 d][32 m-chunks], swizzled
  f16x8* Plds = (f16x8*)(smem + 32768);    // 4 waves x [16 n][32 m-chunks]

  const int tid = threadIdx.x;
  const int bh = blockIdx.x;
  const int b = bh / 12, h = bh - b * 12;
  const int lane = tid & 63, wid = tid >> 6;
  const int l15 = lane & 15, g4 = lane >> 4;

  f16x8 z8;
#pragma unroll
  for (int j = 0; j < 8; ++j) z8[j] = (f16)0.f;

  const f16* vgb = vTg + (size_t)bh * (64 * 224);
  for (int c = tid; c < 64 * 32; c += 256) {
    int d = c >> 5, mc = c & 31;
    f16x8 v;
    if (mc < 24) {
      v = *(const f16x8*)(vgb + d * 224 + mc * 8);
    } else if (mc == 24) {
      v = *(const f16x8*)(vgb + d * 224 + mc * 8);
#pragma unroll
      for (int j = 4; j < 8; ++j) v[j] = (f16)0.f;
    } else {
      v = z8;
    }
    Vlds[d * 32 + (mc ^ (d & 7))] = v;
  }
  f16x8* Pw = Plds + wid * (16 * 32);
  if (g4 < 2) {
    int n = l15;
    Pw[n * 32 + ((26 + g4) ^ (n & 7))] = z8;
  }
  __syncthreads();

  const f16* qgb = qg + (size_t)bh * (196 * 64);
  const f16* kgb = kg + (size_t)bh * (196 * 64);
  const f16* rpbh = rpb + (size_t)h * (196 * 196);

  for (int rt = wid; rt < 13; rt += 4) {
    const int n0 = rt * 16;
    f16x8 qf0 = *(const f16x8*)(qgb + (n0 + l15) * 64 + g4 * 8);
    f16x8 qf1 = *(const f16x8*)(qgb + (n0 + l15) * 64 + 32 + g4 * 8);

    float rv[13][4];
#pragma unroll
    for (int mt = 0; mt < 13; ++mt) {
      const int m = mt * 16 + l15;
      const int mcl = (m < 196) ? m : 195;
#pragma unroll
      for (int r = 0; r < 4; ++r) {
        const int n = n0 + g4 * 4 + r;
        const int ncl = (n < 196) ? n : 195;
        rv[mt][r] = (float)rpbh[ncl * 196 + mcl];
      }
    }

    const f32x4 zero4 = {0.f, 0.f, 0.f, 0.f};
    f32x4 s[13];
#pragma unroll
    for (int mt = 0; mt < 13; ++mt) {
      const int m = mt * 16 + l15;
      f16x8 k0 = *(const f16x8*)(kgb + m * 64 + g4 * 8);
      f16x8 k1 = *(const f16x8*)(kgb + m * 64 + 32 + g4 * 8);
      s[mt] = MFMA16(qf0, k0, zero4, 0, 0, 0);
      s[mt] = MFMA16(qf1, k1, s[mt], 0, 0, 0);
    }

    float mx[4] = {-3e38f, -3e38f, -3e38f, -3e38f};
#pragma unroll
    for (int mt = 0; mt < 13; ++mt) {
      const int m = mt * 16 + l15;
#pragma unroll
      for (int r = 0; r < 4; ++r) {
        const int n = n0 + g4 * 4 + r;
        float v = (m < 196 && n < 196) ? s[mt][r] + rv[mt][r] : -1e30f;
        s[mt][r] = v;
        mx[r] = fmaxf(mx[r], v);
      }
    }
#pragma unroll
    for (int r = 0; r < 4; ++r) {
      mx[r] = fmaxf(mx[r], __shfl_xor(mx[r], 1));
      mx[r] = fmaxf(mx[r], __shfl_xor(mx[r], 2));
      mx[r] = fmaxf(mx[r], __shfl_xor(mx[r], 4));
      mx[r] = fmaxf(mx[r], __shfl_xor(mx[r], 8));
    }
    float sm[4] = {0.f, 0.f, 0.f, 0.f};
#pragma unroll
    for (int mt = 0; mt < 13; ++mt)
#pragma unroll
      for (int r = 0; r < 4; ++r) {
        float p = __expf(s[mt][r] - mx[r]);
        s[mt][r] = p;
        sm[r] += p;
      }
#pragma unroll
    for (int r = 0; r < 4; ++r) {
      sm[r] += __shfl_xor(sm[r], 1);
      sm[r] += __shfl_xor(sm[r], 2);
      sm[r] += __shfl_xor(sm[r], 4);
      sm[r] += __shfl_xor(sm[r], 8);
    }
    float rinv[4];
#pragma unroll
    for (int r = 0; r < 4; ++r) rinv[r] = 1.f / sm[r];

#pragma unroll
    for (int mt = 0; mt < 13; ++mt) {
      const int m = mt * 16 + l15;
#pragma unroll
      for (int r = 0; r < 4; ++r) {
        const int n = g4 * 4 + r;
        f16* dst = (f16*)Pw + n * 256 + (((m >> 3) ^ (n & 7)) << 3) + (m & 7);
        *dst = (f16)s[mt][r];
      }
    }

    f32x4 o[4];
#pragma unroll
    for (int dt = 0; dt < 4; ++dt) o[dt] = zero4;
#pragma unroll
    for (int ks = 0; ks < 7; ++ks) {
      f16x8 pa = Pw[l15 * 32 + ((ks * 4 + g4) ^ (l15 & 7))];
#pragma unroll
      for (int dt = 0; dt < 4; ++dt) {
        const int d = dt * 16 + l15;
        f16x8 vf = Vlds[d * 32 + ((ks * 4 + g4) ^ (d & 7))];
        o[dt] = MFMA16(pa, vf, o[dt], 0, 0, 0);
      }
    }

#pragma unroll
    for (int r = 0; r < 4; ++r) {
      const int n = n0 + g4 * 4 + r;
      if (n < 196) {
        f16* orow = og + ((size_t)b * 196 + n) * 768 + h * 64;
#pragma unroll
        for (int dt = 0; dt < 4; ++dt)
          orow[dt * 16 + l15] = (f16)(o[dt][r] * rinv[r]);
      }
    }
  }
}

// ------------------------------- launcher ---------------------------------------
extern "C" void kernel_launch(void* const* d_in, const int* in_sizes, int n_in,
                              void* d_out, int out_size, void* d_ws, size_t ws_size,
                              hipStream_t stream) {
  const float* x = (const float*)d_in[0];
  const float* qkv_w = (const float*)d_in[1];
  const float* q_bias = (const float*)d_in[2];
  const float* v_bias = (const float*)d_in[3];
  const float* rpb_tab = (const float*)d_in[4];
  const float* proj_w = (const float*)d_in[5];
  const float* proj_b = (const float*)d_in[6];
  const int* rel = (const int*)d_in[7];
  float* out = (float*)d_out;

  const size_t SZ_Q = 77070336;   // [3072][196][64] f16
  const size_t SZ_K = 77070336;
  const size_t SZ_VT = 88080384;  // [3072][64][224] f16
  const size_t SZ_AO = 77070336;  // [50176][768] f16 (also hosts xh before attn)
  const size_t SZ_RP = 921984;    // [12][196][196] f16
  const size_t SZ_WQ = 3538944;   // [2304][768] f16
  const size_t SZ_WP = 1179648;   // [768][768] f16
  if (ws_size < SZ_Q + SZ_K + SZ_VT + SZ_AO + SZ_RP + SZ_WQ + SZ_WP) return;

  char* w = (char*)d_ws;
  f16* q_ = (f16*)w;
  f16* k_ = (f16*)(w + SZ_Q);
  f16* vT_ = (f16*)(w + SZ_Q + SZ_K);
  f16* ao_ = (f16*)(w + SZ_Q + SZ_K + SZ_VT);
  f16* rp_ = (f16*)(w + SZ_Q + SZ_K + SZ_VT + SZ_AO);
  f16* whq_ = (f16*)(w + SZ_Q + SZ_K + SZ_VT + SZ_AO + SZ_RP);
  f16* whp_ = (f16*)(w + SZ_Q + SZ_K + SZ_VT + SZ_AO + SZ_RP + SZ_WQ);
  f16* xh_ = ao_;  // alias: xh dead before attn writes ao_

  (void)hipFuncSetAttribute((const void*)attn_k,
                            hipFuncAttributeMaxDynamicSharedMemorySize, 65536);
  (void)hipFuncSetAttribute((const void*)gemm_k<0>,
                            hipFuncAttributeMaxDynamicSharedMemorySize, 131072);
  (void)hipFuncSetAttribute((const void*)gemm_k<1>,
                            hipFuncAttributeMaxDynamicSharedMemorySize, 131072);

  cvt_k<<<2048, 256, 0, stream>>>(x, xh_, 50176 * 768 / 8);
  cvt_k<<<864, 256, 0, stream>>>(qkv_w, whq_, 2304 * 768 / 8);
  cvt_k<<<288, 256, 0, stream>>>(proj_w, whp_, 768 * 768 / 8);
  rpb_build_k<<<(196 * 196 + 255) / 256, 256, 0, stream>>>(rpb_tab, rel, rp_);

  gemm_k<0><<<1764, 512, 131072, stream>>>(xh_, whq_, q_bias, v_bias,
                                           q_, k_, vT_, nullptr);
  attn_k<<<3072, 256, 65536, stream>>>(q_, k_, vT_, rp_, ao_);
  gemm_k<1><<<588, 512, 131072, stream>>>(ao_, whp_, proj_b, nullptr,
                                          nullptr, nullptr, nullptr, out);
}

// Round 7
// 803.212 us; speedup vs baseline: 1.3044x; 1.3044x over previous
//
#include <hip/hip_runtime.h>
#include <hip/hip_fp16.h>

typedef _Float16 f16;
typedef __attribute__((ext_vector_type(8))) _Float16 f16x8;
typedef __attribute__((ext_vector_type(4))) float f32x4;

#define MFMA16 __builtin_amdgcn_mfma_f32_16x16x32_f16
#define BAR() __builtin_amdgcn_s_barrier()
#define VMCNT(n) asm volatile("s_waitcnt vmcnt(" #n ")" ::: "memory")
#define LGKM(n) asm volatile("s_waitcnt lgkmcnt(" #n ")" ::: "memory")
#define SCHEDB() __builtin_amdgcn_sched_barrier(0)

__device__ __forceinline__ void gload16(const f16* g, char* l) {
  __builtin_amdgcn_global_load_lds(
      (const __attribute__((address_space(1))) void*)g,
      (__attribute__((address_space(3))) void*)l, 16, 0, 0);
}

// ---------------- fp32 -> fp16 bulk convert (nt loads: one-shot stream) ----------
__global__ __launch_bounds__(256) void cvt_k(const float* __restrict__ in,
                                             f16* __restrict__ out, int n8) {
  int i = blockIdx.x * 256 + threadIdx.x;
  const int stride = gridDim.x * 256;
  for (; i < n8; i += stride) {
    const f32x4* p = (const f32x4*)(in + (size_t)i * 8);
    f32x4 a = __builtin_nontemporal_load(p);
    f32x4 b = __builtin_nontemporal_load(p + 1);
    f16x8 h;
    h[0] = (f16)a[0]; h[1] = (f16)a[1]; h[2] = (f16)a[2]; h[3] = (f16)a[3];
    h[4] = (f16)b[0]; h[5] = (f16)b[1]; h[6] = (f16)b[2]; h[7] = (f16)b[3];
    *(f16x8*)(out + (size_t)i * 8) = h;  // normal store: re-read by gemm soon
  }
}

// ---------------- rpb gather ----------------
__global__ __launch_bounds__(256) void rpb_build_k(const float* __restrict__ tab,
                                                   const int* __restrict__ rel,
                                                   f16* __restrict__ out) {
  int i = blockIdx.x * 256 + threadIdx.x;
  if (i >= 196 * 196) return;
  int idx = __builtin_nontemporal_load(rel + i);
#pragma unroll
  for (int h = 0; h < 12; ++h)
    out[h * (196 * 196) + i] = (f16)tab[idx * 12 + h];
}

// ---------------- 256x256 GEMM, counted-vmcnt pipeline -------------------------
// 512 thr / 8 waves (2Mx4N), BK=64, LDS 128KB dbuf, swizzled chunks.
// Iter t: issue tile t+1's 8 loads, VMCNT(8) (= tile t landed; t+1 stays in
// flight ACROSS the barrier), BAR, ds_read+MFMA tile t, BAR. No full drain in
// the main loop -> HBM latency of t+1 hides under t's whole compute phase.
template <int MODE>
__global__ __launch_bounds__(512) void gemm_k(
    const f16* __restrict__ A, const f16* __restrict__ W,
    const float* __restrict__ bias_a, const float* __restrict__ bias_b,
    f16* __restrict__ q_out, f16* __restrict__ k_out, f16* __restrict__ vT_out,
    float* __restrict__ f_out) {
  constexpr int NTIL = (MODE == 0) ? 9 : 3;     // 2304/256 or 768/256
  constexpr int NWG = 196 * NTIL;
  constexpr int QX = NWG / 8, RX = NWG % 8;
  constexpr int KT = 12;                        // 768/64

  extern __shared__ char lds[];  // [2 buf][A 32K | B 32K]; row = 64 f16 = 128B

  const int tid = threadIdx.x;
  const int lane = tid & 63, wid = tid >> 6;
  const int xcd = blockIdx.x & 7, bix = blockIdx.x >> 3;
  const int lbid =
      (xcd < RX ? xcd * (QX + 1) : RX * (QX + 1) + (xcd - RX) * QX) + bix;
  const int brow = lbid / NTIL, bcol = lbid % NTIL;
  const int wr = wid >> 2, wc = wid & 3;
  const int l15 = lane & 15, g4 = lane >> 4;

  // staging: thread covers row sr of each 64-row quarter; pre-swizzled k-chunk
  const int sr = wid * 8 + (lane >> 3);
  const int scw = ((lane & 7) ^ (lane >> 3)) * 8;
  const f16* pAt = A + (size_t)(brow * 256 + sr) * 768 + scw;
  const f16* pBt = W + (size_t)(bcol * 256 + sr) * 768 + scw;
  char* ldsW = lds + wid * 1024;  // wave-uniform; HW adds lane*16

  auto stA = [&](int kt, int hf, int buf) {
#pragma unroll
    for (int i = 0; i < 2; ++i)
      gload16(pAt + (size_t)(hf * 128 + i * 64) * 768 + kt * 64,
              ldsW + buf * 65536 + hf * 16384 + i * 8192);
  };
  auto stB = [&](int kt, int hf, int buf) {
#pragma unroll
    for (int i = 0; i < 2; ++i)
      gload16(pBt + (size_t)(hf * 128 + i * 64) * 768 + kt * 64,
              ldsW + buf * 65536 + 32768 + hf * 16384 + i * 8192);
  };

  f16x8 af[2][4][2], bf[2][2][2];
  const int aswz = l15 & 7;
  const char* ldsAl = lds + (size_t)(wr * 128 + l15) * 128;
  const char* ldsBl = lds + 32768 + (size_t)(wc * 64 + l15) * 128;

  auto rdA = [&](int q, int buf) {
#pragma unroll
    for (int mf = 0; mf < 4; ++mf)
#pragma unroll
      for (int ks = 0; ks < 2; ++ks)
        af[q][mf][ks] = *(const f16x8*)(ldsAl + buf * 65536 +
                                        (q * 64 + mf * 16) * 128 +
                                        ((ks * 4 + g4) ^ aswz) * 16);
  };
  auto rdB = [&](int r, int buf) {
#pragma unroll
    for (int nf = 0; nf < 2; ++nf)
#pragma unroll
      for (int ks = 0; ks < 2; ++ks)
        bf[r][nf][ks] = *(const f16x8*)(ldsBl + buf * 65536 +
                                        (r * 32 + nf * 16) * 128 +
                                        ((ks * 4 + g4) ^ aswz) * 16);
  };

  const f32x4 zero4 = {0.f, 0.f, 0.f, 0.f};
  f32x4 acc[8][4];
#pragma unroll
  for (int i = 0; i < 8; ++i)
#pragma unroll
    for (int j = 0; j < 4; ++j) acc[i][j] = zero4;

  auto mm = [&](int q, int r) {
#pragma unroll
    for (int ks = 0; ks < 2; ++ks)
#pragma unroll
      for (int mf = 0; mf < 4; ++mf)
#pragma unroll
        for (int nf = 0; nf < 2; ++nf)
          acc[q * 4 + mf][r * 2 + nf] =
              MFMA16(af[q][mf][ks], bf[r][nf][ks], acc[q * 4 + mf][r * 2 + nf],
                     0, 0, 0);
  };

  // prologue: stage tile 0, full drain once
  stA(0, 0, 0); stA(0, 1, 0); stB(0, 0, 0); stB(0, 1, 0);
  VMCNT(0);
  BAR();

  for (int t = 0; t < KT; ++t) {
    const int cur = t & 1, nxt = cur ^ 1;
    if (t + 1 < KT) {
      // issue tile t+1 (8 loads), then wait only until tile t's loads landed;
      // tile t+1's 8 remain in flight across the barrier (counted vmcnt, T4)
      stA(t + 1, 0, nxt); stA(t + 1, 1, nxt);
      stB(t + 1, 0, nxt); stB(t + 1, 1, nxt);
      VMCNT(8);
    } else {
      VMCNT(0);  // last tile: drain
    }
    BAR();  // all waves' tile-t stage-writes visible in LDS
    rdA(0, cur); rdB(0, cur);
    SCHEDB();
    rdA(1, cur); rdB(1, cur);
    LGKM(12);
    SCHEDB();
    __builtin_amdgcn_s_setprio(1); mm(0, 0); mm(0, 1); __builtin_amdgcn_s_setprio(0);
    LGKM(0);
    SCHEDB();
    __builtin_amdgcn_s_setprio(1); mm(1, 0); mm(1, 1); __builtin_amdgcn_s_setprio(0);
    BAR();  // all waves done reading buf cur before t+2's stages overwrite it
  }

  // ---- epilogue (normal cached stores) ----
#pragma unroll
  for (int mf = 0; mf < 8; ++mf) {
    const int rowo = wr * 128 + (mf >> 2) * 64 + (mf & 3) * 16 + g4 * 4;
#pragma unroll
    for (int rr = 0; rr < 4; ++rr) {
      const int grow = brow * 256 + rowo + rr;
      if constexpr (MODE == 0) {
        const int bI = grow / 196;
        const int nI = grow - bI * 196;
#pragma unroll
        for (int nf = 0; nf < 4; ++nf) {
          const int col = bcol * 256 + wc * 64 + (nf >> 1) * 32 + (nf & 1) * 16 + l15;
          const int s = bcol / 3;
          const int rem = col - s * 768;
          const int hh = rem >> 6, dd = rem & 63;
          float v = acc[mf][nf][rr];
          if (s == 0) {
            v = (v + bias_a[rem]) * 0.125f;
            q_out[(((size_t)bI * 12 + hh) * 196 + nI) * 64 + dd] = (f16)v;
          } else if (s == 1) {
            k_out[(((size_t)bI * 12 + hh) * 196 + nI) * 64 + dd] = (f16)v;
          } else {
            v += bias_b[rem];
            vT_out[(((size_t)bI * 12 + hh) * 64 + dd) * 224 + nI] = (f16)v;
          }
        }
      } else {
        float* orow = f_out + (size_t)grow * 768;
#pragma unroll
        for (int nf = 0; nf < 4; ++nf) {
          const int col = bcol * 256 + wc * 64 + (nf >> 1) * 32 + (nf & 1) * 16 + l15;
          orow[col] = acc[mf][nf][rr] + bias_a[col];
        }
      }
    }
  }
}

// ---------------- fused window attention: one WG (4 waves) per (b,h) -------------
// V + P in LDS (64KB -> 2 blocks/CU); K, Q, rpb direct from global.
__global__ __launch_bounds__(256) void attn_k(const f16* __restrict__ qg,
                                              const f16* __restrict__ kg,
                                              const f16* __restrict__ vTg,
                                              const f16* __restrict__ rpb,
                                              f16* __restrict__ og) {
  extern __shared__ char smem[];
  f16x8* Vlds = (f16x8*)smem;              // [64 d][32 m-chunks], swizzled
  f16x8* Plds = (f16x8*)(smem + 32768);    // 4 waves x [16 n][32 m-chunks]

  const int tid = threadIdx.x;
  const int bh = blockIdx.x;
  const int b = bh / 12, h = bh - b * 12;
  const int lane = tid & 63, wid = tid >> 6;
  const int l15 = lane & 15, g4 = lane >> 4;

  f16x8 z8;
#pragma unroll
  for (int j = 0; j < 8; ++j) z8[j] = (f16)0.f;

  const f16* vgb = vTg + (size_t)bh * (64 * 224);
  for (int c = tid; c < 64 * 32; c += 256) {
    int d = c >> 5, mc = c & 31;
    f16x8 v;
    if (mc < 24) {
      v = *(const f16x8*)(vgb + d * 224 + mc * 8);
    } else if (mc == 24) {
      v = *(const f16x8*)(vgb + d * 224 + mc * 8);
#pragma unroll
      for (int j = 4; j < 8; ++j) v[j] = (f16)0.f;
    } else {
      v = z8;
    }
    Vlds[d * 32 + (mc ^ (d & 7))] = v;
  }
  f16x8* Pw = Plds + wid * (16 * 32);
  if (g4 < 2) {
    int n = l15;
    Pw[n * 32 + ((26 + g4) ^ (n & 7))] = z8;
  }
  __syncthreads();

  const f16* qgb = qg + (size_t)bh * (196 * 64);
  const f16* kgb = kg + (size_t)bh * (196 * 64);
  const f16* rpbh = rpb + (size_t)h * (196 * 196);

  for (int rt = wid; rt < 13; rt += 4) {
    const int n0 = rt * 16;
    f16x8 qf0 = *(const f16x8*)(qgb + (n0 + l15) * 64 + g4 * 8);
    f16x8 qf1 = *(const f16x8*)(qgb + (n0 + l15) * 64 + 32 + g4 * 8);

    float rv[13][4];
#pragma unroll
    for (int mt = 0; mt < 13; ++mt) {
      const int m = mt * 16 + l15;
      const int mcl = (m < 196) ? m : 195;
#pragma unroll
      for (int r = 0; r < 4; ++r) {
        const int n = n0 + g4 * 4 + r;
        const int ncl = (n < 196) ? n : 195;
        rv[mt][r] = (float)rpbh[ncl * 196 + mcl];
      }
    }

    const f32x4 zero4 = {0.f, 0.f, 0.f, 0.f};
    f32x4 s[13];
#pragma unroll
    for (int mt = 0; mt < 13; ++mt) {
      const int m = mt * 16 + l15;
      f16x8 k0 = *(const f16x8*)(kgb + m * 64 + g4 * 8);
      f16x8 k1 = *(const f16x8*)(kgb + m * 64 + 32 + g4 * 8);
      s[mt] = MFMA16(qf0, k0, zero4, 0, 0, 0);
      s[mt] = MFMA16(qf1, k1, s[mt], 0, 0, 0);
    }

    float mx[4] = {-3e38f, -3e38f, -3e38f, -3e38f};
#pragma unroll
    for (int mt = 0; mt < 13; ++mt) {
      const int m = mt * 16 + l15;
#pragma unroll
      for (int r = 0; r < 4; ++r) {
        const int n = n0 + g4 * 4 + r;
        float v = (m < 196 && n < 196) ? s[mt][r] + rv[mt][r] : -1e30f;
        s[mt][r] = v;
        mx[r] = fmaxf(mx[r], v);
      }
    }
#pragma unroll
    for (int r = 0; r < 4; ++r) {
      mx[r] = fmaxf(mx[r], __shfl_xor(mx[r], 1));
      mx[r] = fmaxf(mx[r], __shfl_xor(mx[r], 2));
      mx[r] = fmaxf(mx[r], __shfl_xor(mx[r], 4));
      mx[r] = fmaxf(mx[r], __shfl_xor(mx[r], 8));
    }
    float sm[4] = {0.f, 0.f, 0.f, 0.f};
#pragma unroll
    for (int mt = 0; mt < 13; ++mt)
#pragma unroll
      for (int r = 0; r < 4; ++r) {
        float p = __expf(s[mt][r] - mx[r]);
        s[mt][r] = p;
        sm[r] += p;
      }
#pragma unroll
    for (int r = 0; r < 4; ++r) {
      sm[r] += __shfl_xor(sm[r], 1);
      sm[r] += __shfl_xor(sm[r], 2);
      sm[r] += __shfl_xor(sm[r], 4);
      sm[r] += __shfl_xor(sm[r], 8);
    }
    float rinv[4];
#pragma unroll
    for (int r = 0; r < 4; ++r) rinv[r] = 1.f / sm[r];

#pragma unroll
    for (int mt = 0; mt < 13; ++mt) {
      const int m = mt * 16 + l15;
#pragma unroll
      for (int r = 0; r < 4; ++r) {
        const int n = g4 * 4 + r;
        f16* dst = (f16*)Pw + n * 256 + (((m >> 3) ^ (n & 7)) << 3) + (m & 7);
        *dst = (f16)s[mt][r];
      }
    }

    f32x4 o[4];
#pragma unroll
    for (int dt = 0; dt < 4; ++dt) o[dt] = zero4;
#pragma unroll
    for (int ks = 0; ks < 7; ++ks) {
      f16x8 pa = Pw[l15 * 32 + ((ks * 4 + g4) ^ (l15 & 7))];
#pragma unroll
      for (int dt = 0; dt < 4; ++dt) {
        const int d = dt * 16 + l15;
        f16x8 vf = Vlds[d * 32 + ((ks * 4 + g4) ^ (d & 7))];
        o[dt] = MFMA16(pa, vf, o[dt], 0, 0, 0);
      }
    }

#pragma unroll
    for (int r = 0; r < 4; ++r) {
      const int n = n0 + g4 * 4 + r;
      if (n < 196) {
        f16* orow = og + ((size_t)b * 196 + n) * 768 + h * 64;
#pragma unroll
        for (int dt = 0; dt < 4; ++dt)
          orow[dt * 16 + l15] = (f16)(o[dt][r] * rinv[r]);
      }
    }
  }
}

// ------------------------------- launcher ---------------------------------------
extern "C" void kernel_launch(void* const* d_in, const int* in_sizes, int n_in,
                              void* d_out, int out_size, void* d_ws, size_t ws_size,
                              hipStream_t stream) {
  const float* x = (const float*)d_in[0];
  const float* qkv_w = (const float*)d_in[1];
  const float* q_bias = (const float*)d_in[2];
  const float* v_bias = (const float*)d_in[3];
  const float* rpb_tab = (const float*)d_in[4];
  const float* proj_w = (const float*)d_in[5];
  const float* proj_b = (const float*)d_in[6];
  const int* rel = (const int*)d_in[7];
  float* out = (float*)d_out;

  const size_t SZ_Q = 77070336;   // [3072][196][64] f16
  const size_t SZ_K = 77070336;
  const size_t SZ_VT = 88080384;  // [3072][64][224] f16
  const size_t SZ_AO = 77070336;  // [50176][768] f16 (also hosts xh before attn)
  const size_t SZ_RP = 921984;    // [12][196][196] f16
  const size_t SZ_WQ = 3538944;   // [2304][768] f16
  const size_t SZ_WP = 1179648;   // [768][768] f16
  if (ws_size < SZ_Q + SZ_K + SZ_VT + SZ_AO + SZ_RP + SZ_WQ + SZ_WP) return;

  char* w = (char*)d_ws;
  f16* q_ = (f16*)w;
  f16* k_ = (f16*)(w + SZ_Q);
  f16* vT_ = (f16*)(w + SZ_Q + SZ_K);
  f16* ao_ = (f16*)(w + SZ_Q + SZ_K + SZ_VT);
  f16* rp_ = (f16*)(w + SZ_Q + SZ_K + SZ_VT + SZ_AO);
  f16* whq_ = (f16*)(w + SZ_Q + SZ_K + SZ_VT + SZ_AO + SZ_RP);
  f16* whp_ = (f16*)(w + SZ_Q + SZ_K + SZ_VT + SZ_AO + SZ_RP + SZ_WQ);
  f16* xh_ = ao_;  // alias: xh dead before attn writes ao_

  (void)hipFuncSetAttribute((const void*)attn_k,
                            hipFuncAttributeMaxDynamicSharedMemorySize, 65536);
  (void)hipFuncSetAttribute((const void*)gemm_k<0>,
                            hipFuncAttributeMaxDynamicSharedMemorySize, 131072);
  (void)hipFuncSetAttribute((const void*)gemm_k<1>,
                            hipFuncAttributeMaxDynamicSharedMemorySize, 131072);

  cvt_k<<<2048, 256, 0, stream>>>(x, xh_, 50176 * 768 / 8);
  cvt_k<<<864, 256, 0, stream>>>(qkv_w, whq_, 2304 * 768 / 8);
  cvt_k<<<288, 256, 0, stream>>>(proj_w, whp_, 768 * 768 / 8);
  rpb_build_k<<<(196 * 196 + 255) / 256, 256, 0, stream>>>(rpb_tab, rel, rp_);

  gemm_k<0><<<1764, 512, 131072, stream>>>(xh_, whq_, q_bias, v_bias,
                                           q_, k_, vT_, nullptr);
  attn_k<<<3072, 256, 65536, stream>>>(q_, k_, vT_, rp_, ao_);
  gemm_k<1><<<588, 512, 131072, stream>>>(ao_, whp_, proj_b, nullptr,
                                          nullptr, nullptr, nullptr, out);
}

// Round 8
// 767.361 us; speedup vs baseline: 1.3653x; 1.0467x over previous
//
#include <hip/hip_runtime.h>
#include <hip/hip_fp16.h>

typedef _Float16 f16;
typedef __attribute__((ext_vector_type(8))) _Float16 f16x8;
typedef __attribute__((ext_vector_type(4))) float f32x4;

#define MFMA16 __builtin_amdgcn_mfma_f32_16x16x32_f16
#define BAR() __builtin_amdgcn_s_barrier()
#define VMCNT(n) asm volatile("s_waitcnt vmcnt(" #n ")" ::: "memory")
#define LGKM(n) asm volatile("s_waitcnt lgkmcnt(" #n ")" ::: "memory")
#define SCHEDB() __builtin_amdgcn_sched_barrier(0)

__device__ __forceinline__ void gload16(const f16* g, char* l) {
  __builtin_amdgcn_global_load_lds(
      (const __attribute__((address_space(1))) void*)g,
      (__attribute__((address_space(3))) void*)l, 16, 0, 0);
}

// ---------------- fp32 -> fp16 bulk convert ----------------
__global__ __launch_bounds__(256) void cvt_k(const float* __restrict__ in,
                                             f16* __restrict__ out, int n8) {
  int i = blockIdx.x * 256 + threadIdx.x;
  const int stride = gridDim.x * 256;
  for (; i < n8; i += stride) {
    const f32x4* p = (const f32x4*)(in + (size_t)i * 8);
    f32x4 a = __builtin_nontemporal_load(p);
    f32x4 b = __builtin_nontemporal_load(p + 1);
    f16x8 h;
    h[0] = (f16)a[0]; h[1] = (f16)a[1]; h[2] = (f16)a[2]; h[3] = (f16)a[3];
    h[4] = (f16)b[0]; h[5] = (f16)b[1]; h[6] = (f16)b[2]; h[7] = (f16)b[3];
    *(f16x8*)(out + (size_t)i * 8) = h;
  }
}

// ---------------- rpb gather ----------------
__global__ __launch_bounds__(256) void rpb_build_k(const float* __restrict__ tab,
                                                   const int* __restrict__ rel,
                                                   f16* __restrict__ out) {
  int i = blockIdx.x * 256 + threadIdx.x;
  if (i >= 196 * 196) return;
  int idx = __builtin_nontemporal_load(rel + i);
#pragma unroll
  for (int h = 0; h < 12; ++h)
    out[h * (196 * 196) + i] = (f16)tab[idx * 12 + h];
}

// ---------------- 256x256 GEMM, asymmetric-depth prefetch ------------------------
// A (streaming, HBM-missing) 3-deep; B (L2-hot) 2-deep. LDS = 3*32K + 2*32K = 160K.
// Per iter: VMCNT(4) [forces A(t),B(t); only A(t+2) stays in flight] -> BAR ->
// issue B(t+1), A(t+2) -> ds_read tile t -> MFMA. A-loads get 2 full iterations.
template <int MODE>
__global__ __launch_bounds__(512) void gemm_k(
    const f16* __restrict__ A, const f16* __restrict__ W,
    const float* __restrict__ bias_a, const float* __restrict__ bias_b,
    f16* __restrict__ q_out, f16* __restrict__ k_out, f16* __restrict__ vT_out,
    float* __restrict__ f_out) {
  constexpr int NTIL = (MODE == 0) ? 9 : 3;     // 2304/256 or 768/256
  constexpr int NWG = 196 * NTIL;
  constexpr int QX = NWG / 8, RX = NWG % 8;
  constexpr int KT = 12;                        // 768/64

  extern __shared__ char lds[];  // A: 3 x 32K @0 ; B: 2 x 32K @98304

  const int tid = threadIdx.x;
  const int lane = tid & 63, wid = tid >> 6;
  const int xcd = blockIdx.x & 7, bix = blockIdx.x >> 3;
  const int lbid =
      (xcd < RX ? xcd * (QX + 1) : RX * (QX + 1) + (xcd - RX) * QX) + bix;
  const int brow = lbid / NTIL, bcol = lbid % NTIL;
  const int wr = wid >> 2, wc = wid & 3;
  const int l15 = lane & 15, g4 = lane >> 4;

  // staging: thread covers row sr of each 64-row quarter; pre-swizzled k-chunk
  const int sr = wid * 8 + (lane >> 3);
  const int scw = ((lane & 7) ^ (lane >> 3)) * 8;
  const f16* pAt = A + (size_t)(brow * 256 + sr) * 768 + scw;
  const f16* pBt = W + (size_t)(bcol * 256 + sr) * 768 + scw;
  char* ldsW = lds + wid * 1024;  // wave-uniform; HW adds lane*16

  auto stA = [&](int kt) {  // 4 gloads: rows sr+{0,64,128,192}
    char* base = ldsW + (kt % 3) * 32768;
#pragma unroll
    for (int i = 0; i < 4; ++i)
      gload16(pAt + (size_t)(i * 64) * 768 + kt * 64, base + i * 8192);
  };
  auto stB = [&](int kt) {
    char* base = ldsW + 98304 + (kt & 1) * 32768;
#pragma unroll
    for (int i = 0; i < 4; ++i)
      gload16(pBt + (size_t)(i * 64) * 768 + kt * 64, base + i * 8192);
  };

  f16x8 af[2][4][2], bf[2][2][2];
  const int aswz = l15 & 7;
  const char* ldsAl = lds + (size_t)(wr * 128 + l15) * 128;
  const char* ldsBl = lds + 98304 + (size_t)(wc * 64 + l15) * 128;

  auto rdA = [&](int q, int t) {
    const char* b = ldsAl + (t % 3) * 32768;
#pragma unroll
    for (int mf = 0; mf < 4; ++mf)
#pragma unroll
      for (int ks = 0; ks < 2; ++ks)
        af[q][mf][ks] = *(const f16x8*)(b + (q * 64 + mf * 16) * 128 +
                                        ((ks * 4 + g4) ^ aswz) * 16);
  };
  auto rdB = [&](int r, int t) {
    const char* b = ldsBl + (t & 1) * 32768;
#pragma unroll
    for (int nf = 0; nf < 2; ++nf)
#pragma unroll
      for (int ks = 0; ks < 2; ++ks)
        bf[r][nf][ks] = *(const f16x8*)(b + (r * 32 + nf * 16) * 128 +
                                        ((ks * 4 + g4) ^ aswz) * 16);
  };

  const f32x4 zero4 = {0.f, 0.f, 0.f, 0.f};
  f32x4 acc[8][4];
#pragma unroll
  for (int i = 0; i < 8; ++i)
#pragma unroll
    for (int j = 0; j < 4; ++j) acc[i][j] = zero4;

  auto mm = [&](int q, int r) {
#pragma unroll
    for (int ks = 0; ks < 2; ++ks)
#pragma unroll
      for (int mf = 0; mf < 4; ++mf)
#pragma unroll
        for (int nf = 0; nf < 2; ++nf)
          acc[q * 4 + mf][r * 2 + nf] =
              MFMA16(af[q][mf][ks], bf[r][nf][ks], acc[q * 4 + mf][r * 2 + nf],
                     0, 0, 0);
  };

  // prologue FIFO: A(0)x4, B(0)x4, A(1)x4  (12 in flight)
  stA(0); stB(0); stA(1);

  for (int t = 0; t < KT; ++t) {
    // wait: everything except the newest 4 (A(t+2) when present) has landed
    if (t == KT - 1) { VMCNT(0); } else { VMCNT(4); }
    BAR();  // all waves: tile-t staged & visible; prior-iter reads complete
    if (t + 1 < KT) stB(t + 1);
    if (t + 2 < KT) stA(t + 2);
    rdA(0, t); rdB(0, t);
    SCHEDB();
    rdA(1, t); rdB(1, t);
    LGKM(12);
    SCHEDB();
    __builtin_amdgcn_s_setprio(1); mm(0, 0); mm(0, 1); __builtin_amdgcn_s_setprio(0);
    LGKM(0);
    SCHEDB();
    __builtin_amdgcn_s_setprio(1); mm(1, 0); mm(1, 1); __builtin_amdgcn_s_setprio(0);
  }

  // ---- epilogue ----
#pragma unroll
  for (int mf = 0; mf < 8; ++mf) {
    const int rowo = wr * 128 + (mf >> 2) * 64 + (mf & 3) * 16 + g4 * 4;
#pragma unroll
    for (int rr = 0; rr < 4; ++rr) {
      const int grow = brow * 256 + rowo + rr;
      if constexpr (MODE == 0) {
        const int bI = grow / 196;
        const int nI = grow - bI * 196;
#pragma unroll
        for (int nf = 0; nf < 4; ++nf) {
          const int col = bcol * 256 + wc * 64 + (nf >> 1) * 32 + (nf & 1) * 16 + l15;
          const int s = bcol / 3;
          const int rem = col - s * 768;
          const int hh = rem >> 6, dd = rem & 63;
          float v = acc[mf][nf][rr];
          if (s == 0) {
            v = (v + bias_a[rem]) * 0.125f;
            q_out[(((size_t)bI * 12 + hh) * 196 + nI) * 64 + dd] = (f16)v;
          } else if (s == 1) {
            k_out[(((size_t)bI * 12 + hh) * 196 + nI) * 64 + dd] = (f16)v;
          } else {
            v += bias_b[rem];
            vT_out[(((size_t)bI * 12 + hh) * 64 + dd) * 224 + nI] = (f16)v;
          }
        }
      } else {
        float* orow = f_out + (size_t)grow * 768;
#pragma unroll
        for (int nf = 0; nf < 4; ++nf) {
          const int col = bcol * 256 + wc * 64 + (nf >> 1) * 32 + (nf & 1) * 16 + l15;
          orow[col] = acc[mf][nf][rr] + bias_a[col];
        }
      }
    }
  }
}

// ---------------- fused window attention: one WG (4 waves) per (b,h) -------------
// V + P in LDS (64KB -> 2 blocks/CU); K, Q, rpb direct from global.
__global__ __launch_bounds__(256) void attn_k(const f16* __restrict__ qg,
                                              const f16* __restrict__ kg,
                                              const f16* __restrict__ vTg,
                                              const f16* __restrict__ rpb,
                                              f16* __restrict__ og) {
  extern __shared__ char smem[];
  f16x8* Vlds = (f16x8*)smem;              // [64 d][32 m-chunks], swizzled
  f16x8* Plds = (f16x8*)(smem + 32768);    // 4 waves x [16 n][32 m-chunks]

  const int tid = threadIdx.x;
  const int bh = blockIdx.x;
  const int b = bh / 12, h = bh - b * 12;
  const int lane = tid & 63, wid = tid >> 6;
  const int l15 = lane & 15, g4 = lane >> 4;

  f16x8 z8;
#pragma unroll
  for (int j = 0; j < 8; ++j) z8[j] = (f16)0.f;

  const f16* vgb = vTg + (size_t)bh * (64 * 224);
  for (int c = tid; c < 64 * 32; c += 256) {
    int d = c >> 5, mc = c & 31;
    f16x8 v;
    if (mc < 24) {
      v = *(const f16x8*)(vgb + d * 224 + mc * 8);
    } else if (mc == 24) {
      v = *(const f16x8*)(vgb + d * 224 + mc * 8);
#pragma unroll
      for (int j = 4; j < 8; ++j) v[j] = (f16)0.f;
    } else {
      v = z8;
    }
    Vlds[d * 32 + (mc ^ (d & 7))] = v;
  }
  f16x8* Pw = Plds + wid * (16 * 32);
  if (g4 < 2) {
    int n = l15;
    Pw[n * 32 + ((26 + g4) ^ (n & 7))] = z8;
  }
  __syncthreads();

  const f16* qgb = qg + (size_t)bh * (196 * 64);
  const f16* kgb = kg + (size_t)bh * (196 * 64);
  const f16* rpbh = rpb + (size_t)h * (196 * 196);

  for (int rt = wid; rt < 13; rt += 4) {
    const int n0 = rt * 16;
    f16x8 qf0 = *(const f16x8*)(qgb + (n0 + l15) * 64 + g4 * 8);
    f16x8 qf1 = *(const f16x8*)(qgb + (n0 + l15) * 64 + 32 + g4 * 8);

    float rv[13][4];
#pragma unroll
    for (int mt = 0; mt < 13; ++mt) {
      const int m = mt * 16 + l15;
      const int mcl = (m < 196) ? m : 195;
#pragma unroll
      for (int r = 0; r < 4; ++r) {
        const int n = n0 + g4 * 4 + r;
        const int ncl = (n < 196) ? n : 195;
        rv[mt][r] = (float)rpbh[ncl * 196 + mcl];
      }
    }

    const f32x4 zero4 = {0.f, 0.f, 0.f, 0.f};
    f32x4 s[13];
#pragma unroll
    for (int mt = 0; mt < 13; ++mt) {
      const int m = mt * 16 + l15;
      f16x8 k0 = *(const f16x8*)(kgb + m * 64 + g4 * 8);
      f16x8 k1 = *(const f16x8*)(kgb + m * 64 + 32 + g4 * 8);
      s[mt] = MFMA16(qf0, k0, zero4, 0, 0, 0);
      s[mt] = MFMA16(qf1, k1, s[mt], 0, 0, 0);
    }

    float mx[4] = {-3e38f, -3e38f, -3e38f, -3e38f};
#pragma unroll
    for (int mt = 0; mt < 13; ++mt) {
      const int m = mt * 16 + l15;
#pragma unroll
      for (int r = 0; r < 4; ++r) {
        const int n = n0 + g4 * 4 + r;
        float v = (m < 196 && n < 196) ? s[mt][r] + rv[mt][r] : -1e30f;
        s[mt][r] = v;
        mx[r] = fmaxf(mx[r], v);
      }
    }
#pragma unroll
    for (int r = 0; r < 4; ++r) {
      mx[r] = fmaxf(mx[r], __shfl_xor(mx[r], 1));
      mx[r] = fmaxf(mx[r], __shfl_xor(mx[r], 2));
      mx[r] = fmaxf(mx[r], __shfl_xor(mx[r], 4));
      mx[r] = fmaxf(mx[r], __shfl_xor(mx[r], 8));
    }
    float sm[4] = {0.f, 0.f, 0.f, 0.f};
#pragma unroll
    for (int mt = 0; mt < 13; ++mt)
#pragma unroll
      for (int r = 0; r < 4; ++r) {
        float p = __expf(s[mt][r] - mx[r]);
        s[mt][r] = p;
        sm[r] += p;
      }
#pragma unroll
    for (int r = 0; r < 4; ++r) {
      sm[r] += __shfl_xor(sm[r], 1);
      sm[r] += __shfl_xor(sm[r], 2);
      sm[r] += __shfl_xor(sm[r], 4);
      sm[r] += __shfl_xor(sm[r], 8);
    }
    float rinv[4];
#pragma unroll
    for (int r = 0; r < 4; ++r) rinv[r] = 1.f / sm[r];

#pragma unroll
    for (int mt = 0; mt < 13; ++mt) {
      const int m = mt * 16 + l15;
#pragma unroll
      for (int r = 0; r < 4; ++r) {
        const int n = g4 * 4 + r;
        f16* dst = (f16*)Pw + n * 256 + (((m >> 3) ^ (n & 7)) << 3) + (m & 7);
        *dst = (f16)s[mt][r];
      }
    }

    f32x4 o[4];
#pragma unroll
    for (int dt = 0; dt < 4; ++dt) o[dt] = zero4;
#pragma unroll
    for (int ks = 0; ks < 7; ++ks) {
      f16x8 pa = Pw[l15 * 32 + ((ks * 4 + g4) ^ (l15 & 7))];
#pragma unroll
      for (int dt = 0; dt < 4; ++dt) {
        const int d = dt * 16 + l15;
        f16x8 vf = Vlds[d * 32 + ((ks * 4 + g4) ^ (d & 7))];
        o[dt] = MFMA16(pa, vf, o[dt], 0, 0, 0);
      }
    }

#pragma unroll
    for (int r = 0; r < 4; ++r) {
      const int n = n0 + g4 * 4 + r;
      if (n < 196) {
        f16* orow = og + ((size_t)b * 196 + n) * 768 + h * 64;
#pragma unroll
        for (int dt = 0; dt < 4; ++dt)
          orow[dt * 16 + l15] = (f16)(o[dt][r] * rinv[r]);
      }
    }
  }
}

// ------------------------------- launcher ---------------------------------------
extern "C" void kernel_launch(void* const* d_in, const int* in_sizes, int n_in,
                              void* d_out, int out_size, void* d_ws, size_t ws_size,
                              hipStream_t stream) {
  const float* x = (const float*)d_in[0];
  const float* qkv_w = (const float*)d_in[1];
  const float* q_bias = (const float*)d_in[2];
  const float* v_bias = (const float*)d_in[3];
  const float* rpb_tab = (const float*)d_in[4];
  const float* proj_w = (const float*)d_in[5];
  const float* proj_b = (const float*)d_in[6];
  const int* rel = (const int*)d_in[7];
  float* out = (float*)d_out;

  const size_t SZ_Q = 77070336;   // [3072][196][64] f16
  const size_t SZ_K = 77070336;
  const size_t SZ_VT = 88080384;  // [3072][64][224] f16
  const size_t SZ_AO = 77070336;  // [50176][768] f16 (also hosts xh before attn)
  const size_t SZ_RP = 921984;    // [12][196][196] f16
  const size_t SZ_WQ = 3538944;   // [2304][768] f16
  const size_t SZ_WP = 1179648;   // [768][768] f16
  if (ws_size < SZ_Q + SZ_K + SZ_VT + SZ_AO + SZ_RP + SZ_WQ + SZ_WP) return;

  char* w = (char*)d_ws;
  f16* q_ = (f16*)w;
  f16* k_ = (f16*)(w + SZ_Q);
  f16* vT_ = (f16*)(w + SZ_Q + SZ_K);
  f16* ao_ = (f16*)(w + SZ_Q + SZ_K + SZ_VT);
  f16* rp_ = (f16*)(w + SZ_Q + SZ_K + SZ_VT + SZ_AO);
  f16* whq_ = (f16*)(w + SZ_Q + SZ_K + SZ_VT + SZ_AO + SZ_RP);
  f16* whp_ = (f16*)(w + SZ_Q + SZ_K + SZ_VT + SZ_AO + SZ_RP + SZ_WQ);
  f16* xh_ = ao_;  // alias: xh dead before attn writes ao_

  (void)hipFuncSetAttribute((const void*)attn_k,
                            hipFuncAttributeMaxDynamicSharedMemorySize, 65536);
  (void)hipFuncSetAttribute((const void*)gemm_k<0>,
                            hipFuncAttributeMaxDynamicSharedMemorySize, 163840);
  (void)hipFuncSetAttribute((const void*)gemm_k<1>,
                            hipFuncAttributeMaxDynamicSharedMemorySize, 163840);

  cvt_k<<<2048, 256, 0, stream>>>(x, xh_, 50176 * 768 / 8);
  cvt_k<<<864, 256, 0, stream>>>(qkv_w, whq_, 2304 * 768 / 8);
  cvt_k<<<288, 256, 0, stream>>>(proj_w, whp_, 768 * 768 / 8);
  rpb_build_k<<<(196 * 196 + 255) / 256, 256, 0, stream>>>(rpb_tab, rel, rp_);

  gemm_k<0><<<1764, 512, 163840, stream>>>(xh_, whq_, q_bias, v_bias,
                                           q_, k_, vT_, nullptr);
  attn_k<<<3072, 256, 65536, stream>>>(q_, k_, vT_, rp_, ao_);
  gemm_k<1><<<588, 512, 163840, stream>>>(ao_, whp_, proj_b, nullptr,
                                          nullptr, nullptr, nullptr, out);
}

// Round 9
// 663.123 us; speedup vs baseline: 1.5800x; 1.1572x over previous
//
#include <hip/hip_runtime.h>
#include <hip/hip_fp16.h>

typedef _Float16 f16;
typedef __attribute__((ext_vector_type(4))) _Float16 f16x4;
typedef __attribute__((ext_vector_type(8))) _Float16 f16x8;
typedef __attribute__((ext_vector_type(4))) float f32x4;

#define MFMA16 __builtin_amdgcn_mfma_f32_16x16x32_f16
#define BAR() __builtin_amdgcn_s_barrier()
#define VMCNT(n) asm volatile("s_waitcnt vmcnt(" #n ")" ::: "memory")
#define LGKM(n) asm volatile("s_waitcnt lgkmcnt(" #n ")" ::: "memory")
#define SCHEDB() __builtin_amdgcn_sched_barrier(0)

__device__ __forceinline__ void gload16(const f16* g, char* l) {
  __builtin_amdgcn_global_load_lds(
      (const __attribute__((address_space(1))) void*)g,
      (__attribute__((address_space(3))) void*)l, 16, 0, 0);
}

// ---------------- fp32 -> fp16 bulk convert ----------------
__global__ __launch_bounds__(256) void cvt_k(const float* __restrict__ in,
                                             f16* __restrict__ out, int n8) {
  int i = blockIdx.x * 256 + threadIdx.x;
  const int stride = gridDim.x * 256;
  for (; i < n8; i += stride) {
    const f32x4* p = (const f32x4*)(in + (size_t)i * 8);
    f32x4 a = __builtin_nontemporal_load(p);
    f32x4 b = __builtin_nontemporal_load(p + 1);
    f16x8 h;
    h[0] = (f16)a[0]; h[1] = (f16)a[1]; h[2] = (f16)a[2]; h[3] = (f16)a[3];
    h[4] = (f16)b[0]; h[5] = (f16)b[1]; h[6] = (f16)b[2]; h[7] = (f16)b[3];
    *(f16x8*)(out + (size_t)i * 8) = h;
  }
}

// ---------------- rpb gather ----------------
__global__ __launch_bounds__(256) void rpb_build_k(const float* __restrict__ tab,
                                                   const int* __restrict__ rel,
                                                   f16* __restrict__ out) {
  int i = blockIdx.x * 256 + threadIdx.x;
  if (i >= 196 * 196) return;
  int idx = __builtin_nontemporal_load(rel + i);
#pragma unroll
  for (int h = 0; h < 12; ++h)
    out[h * (196 * 196) + i] = (f16)tab[idx * 12 + h];
}

// ---------------- 256x256 GEMM, bcol-major XCD chunking --------------------------
// bcol = lbid/196: all CUs of an XCD share ONE B panel (393KB, L2-resident) ->
// the 1-deep B(t+1) wait becomes an L2 hit. A streams (no reuse), 3-deep covered.
// LDS: A 3x32K + B 2x32K = 160K. vT epilogue stores vectorized 8B.
template <int MODE>
__global__ __launch_bounds__(512) void gemm_k(
    const f16* __restrict__ A, const f16* __restrict__ W,
    const float* __restrict__ bias_a, const float* __restrict__ bias_b,
    f16* __restrict__ q_out, f16* __restrict__ k_out, f16* __restrict__ vT_out,
    float* __restrict__ f_out) {
  constexpr int NTIL = (MODE == 0) ? 9 : 3;     // 2304/256 or 768/256
  constexpr int NWG = 196 * NTIL;
  constexpr int QX = NWG / 8, RX = NWG % 8;
  constexpr int KT = 12;                        // 768/64

  extern __shared__ char lds[];  // A: 3 x 32K @0 ; B: 2 x 32K @98304

  const int tid = threadIdx.x;
  const int lane = tid & 63, wid = tid >> 6;
  const int xcd = blockIdx.x & 7, bix = blockIdx.x >> 3;
  const int lbid =
      (xcd < RX ? xcd * (QX + 1) : RX * (QX + 1) + (xcd - RX) * QX) + bix;
  const int bcol = lbid / 196, brow = lbid % 196;  // bcol-major within XCD chunk
  const int wr = wid >> 2, wc = wid & 3;
  const int l15 = lane & 15, g4 = lane >> 4;

  // staging: thread covers row sr of each 64-row quarter; pre-swizzled k-chunk
  const int sr = wid * 8 + (lane >> 3);
  const int scw = ((lane & 7) ^ (lane >> 3)) * 8;
  const f16* pAt = A + (size_t)(brow * 256 + sr) * 768 + scw;
  const f16* pBt = W + (size_t)(bcol * 256 + sr) * 768 + scw;
  char* ldsW = lds + wid * 1024;  // wave-uniform; HW adds lane*16

  auto stA = [&](int kt) {  // 4 gloads: rows sr+{0,64,128,192}
    char* base = ldsW + (kt % 3) * 32768;
#pragma unroll
    for (int i = 0; i < 4; ++i)
      gload16(pAt + (size_t)(i * 64) * 768 + kt * 64, base + i * 8192);
  };
  auto stB = [&](int kt) {
    char* base = ldsW + 98304 + (kt & 1) * 32768;
#pragma unroll
    for (int i = 0; i < 4; ++i)
      gload16(pBt + (size_t)(i * 64) * 768 + kt * 64, base + i * 8192);
  };

  f16x8 af[2][4][2], bf[2][2][2];
  const int aswz = l15 & 7;
  const char* ldsAl = lds + (size_t)(wr * 128 + l15) * 128;
  const char* ldsBl = lds + 98304 + (size_t)(wc * 64 + l15) * 128;

  auto rdA = [&](int q, int t) {
    const char* b = ldsAl + (t % 3) * 32768;
#pragma unroll
    for (int mf = 0; mf < 4; ++mf)
#pragma unroll
      for (int ks = 0; ks < 2; ++ks)
        af[q][mf][ks] = *(const f16x8*)(b + (q * 64 + mf * 16) * 128 +
                                        ((ks * 4 + g4) ^ aswz) * 16);
  };
  auto rdB = [&](int r, int t) {
    const char* b = ldsBl + (t & 1) * 32768;
#pragma unroll
    for (int nf = 0; nf < 2; ++nf)
#pragma unroll
      for (int ks = 0; ks < 2; ++ks)
        bf[r][nf][ks] = *(const f16x8*)(b + (r * 32 + nf * 16) * 128 +
                                        ((ks * 4 + g4) ^ aswz) * 16);
  };

  const f32x4 zero4 = {0.f, 0.f, 0.f, 0.f};
  f32x4 acc[8][4];
#pragma unroll
  for (int i = 0; i < 8; ++i)
#pragma unroll
    for (int j = 0; j < 4; ++j) acc[i][j] = zero4;

  auto mm = [&](int q, int r) {
#pragma unroll
    for (int ks = 0; ks < 2; ++ks)
#pragma unroll
      for (int mf = 0; mf < 4; ++mf)
#pragma unroll
        for (int nf = 0; nf < 2; ++nf)
          acc[q * 4 + mf][r * 2 + nf] =
              MFMA16(af[q][mf][ks], bf[r][nf][ks], acc[q * 4 + mf][r * 2 + nf],
                     0, 0, 0);
  };

  // prologue FIFO: A(0)x4, B(0)x4, A(1)x4  (12 in flight)
  stA(0); stB(0); stA(1);

  for (int t = 0; t < KT; ++t) {
    // wait: everything except the newest 4 (A(t+2) when present) has landed
    if (t == KT - 1) { VMCNT(0); } else { VMCNT(4); }
    BAR();  // all waves: tile-t staged & visible; prior-iter reads complete
    if (t + 1 < KT) stB(t + 1);
    if (t + 2 < KT) stA(t + 2);
    rdA(0, t); rdB(0, t);
    SCHEDB();
    rdA(1, t); rdB(1, t);
    LGKM(12);
    SCHEDB();
    __builtin_amdgcn_s_setprio(1); mm(0, 0); mm(0, 1); __builtin_amdgcn_s_setprio(0);
    LGKM(0);
    SCHEDB();
    __builtin_amdgcn_s_setprio(1); mm(1, 0); mm(1, 1); __builtin_amdgcn_s_setprio(0);
  }

  // ---- epilogue ----
  if constexpr (MODE == 0) {
    const int s = bcol / 3;  // uniform per WG
#pragma unroll
    for (int mf = 0; mf < 8; ++mf) {
      const int rowo = wr * 128 + (mf >> 2) * 64 + (mf & 3) * 16 + g4 * 4;
      const int grow0 = brow * 256 + rowo;
      const int bI = grow0 / 196;          // 4-aligned row group: no straddle
      const int nI0 = grow0 - bI * 196;
#pragma unroll
      for (int nf = 0; nf < 4; ++nf) {
        const int col = bcol * 256 + wc * 64 + (nf >> 1) * 32 + (nf & 1) * 16 + l15;
        const int rem = col - s * 768;
        const int hh = rem >> 6, dd = rem & 63;
        if (s == 2) {
          f16x4 vv;
#pragma unroll
          for (int rr = 0; rr < 4; ++rr)
            vv[rr] = (f16)(acc[mf][nf][rr] + bias_b[rem]);
          *(f16x4*)(vT_out + (((size_t)bI * 12 + hh) * 64 + dd) * 224 + nI0) = vv;
        } else if (s == 0) {
#pragma unroll
          for (int rr = 0; rr < 4; ++rr) {
            float v = (acc[mf][nf][rr] + bias_a[rem]) * 0.125f;
            q_out[(((size_t)bI * 12 + hh) * 196 + nI0 + rr) * 64 + dd] = (f16)v;
          }
        } else {
#pragma unroll
          for (int rr = 0; rr < 4; ++rr)
            k_out[(((size_t)bI * 12 + hh) * 196 + nI0 + rr) * 64 + dd] =
                (f16)acc[mf][nf][rr];
        }
      }
    }
  } else {
#pragma unroll
    for (int mf = 0; mf < 8; ++mf) {
      const int rowo = wr * 128 + (mf >> 2) * 64 + (mf & 3) * 16 + g4 * 4;
#pragma unroll
      for (int rr = 0; rr < 4; ++rr) {
        const int grow = brow * 256 + rowo + rr;
        float* orow = f_out + (size_t)grow * 768;
#pragma unroll
        for (int nf = 0; nf < 4; ++nf) {
          const int col = bcol * 256 + wc * 64 + (nf >> 1) * 32 + (nf & 1) * 16 + l15;
          orow[col] = acc[mf][nf][rr] + bias_a[col];
        }
      }
    }
  }
}

// ---------------- fused window attention: one WG (4 waves) per (b,h) -------------
// V + P in LDS (64KB -> 2 blocks/CU); K, Q, rpb direct from global.
__global__ __launch_bounds__(256) void attn_k(const f16* __restrict__ qg,
                                              const f16* __restrict__ kg,
                                              const f16* __restrict__ vTg,
                                              const f16* __restrict__ rpb,
                                              f16* __restrict__ og) {
  extern __shared__ char smem[];
  f16x8* Vlds = (f16x8*)smem;              // [64 d][32 m-chunks], swizzled
  f16x8* Plds = (f16x8*)(smem + 32768);    // 4 waves x [16 n][32 m-chunks]

  const int tid = threadIdx.x;
  const int bh = blockIdx.x;
  const int b = bh / 12, h = bh - b * 12;
  const int lane = tid & 63, wid = tid >> 6;
  const int l15 = lane & 15, g4 = lane >> 4;

  f16x8 z8;
#pragma unroll
  for (int j = 0; j < 8; ++j) z8[j] = (f16)0.f;

  const f16* vgb = vTg + (size_t)bh * (64 * 224);
  for (int c = tid; c < 64 * 32; c += 256) {
    int d = c >> 5, mc = c & 31;
    f16x8 v;
    if (mc < 24) {
      v = *(const f16x8*)(vgb + d * 224 + mc * 8);
    } else if (mc == 24) {
      v = *(const f16x8*)(vgb + d * 224 + mc * 8);
#pragma unroll
      for (int j = 4; j < 8; ++j) v[j] = (f16)0.f;
    } else {
      v = z8;
    }
    Vlds[d * 32 + (mc ^ (d & 7))] = v;
  }
  f16x8* Pw = Plds + wid * (16 * 32);
  if (g4 < 2) {
    int n = l15;
    Pw[n * 32 + ((26 + g4) ^ (n & 7))] = z8;
  }
  __syncthreads();

  const f16* qgb = qg + (size_t)bh * (196 * 64);
  const f16* kgb = kg + (size_t)bh * (196 * 64);
  const f16* rpbh = rpb + (size_t)h * (196 * 196);

  for (int rt = wid; rt < 13; rt += 4) {
    const int n0 = rt * 16;
    f16x8 qf0 = *(const f16x8*)(qgb + (n0 + l15) * 64 + g4 * 8);
    f16x8 qf1 = *(const f16x8*)(qgb + (n0 + l15) * 64 + 32 + g4 * 8);

    float rv[13][4];
#pragma unroll
    for (int mt = 0; mt < 13; ++mt) {
      const int m = mt * 16 + l15;
      const int mcl = (m < 196) ? m : 195;
#pragma unroll
      for (int r = 0; r < 4; ++r) {
        const int n = n0 + g4 * 4 + r;
        const int ncl = (n < 196) ? n : 195;
        rv[mt][r] = (float)rpbh[ncl * 196 + mcl];
      }
    }

    const f32x4 zero4 = {0.f, 0.f, 0.f, 0.f};
    f32x4 s[13];
#pragma unroll
    for (int mt = 0; mt < 13; ++mt) {
      const int m = mt * 16 + l15;
      f16x8 k0 = *(const f16x8*)(kgb + m * 64 + g4 * 8);
      f16x8 k1 = *(const f16x8*)(kgb + m * 64 + 32 + g4 * 8);
      s[mt] = MFMA16(qf0, k0, zero4, 0, 0, 0);
      s[mt] = MFMA16(qf1, k1, s[mt], 0, 0, 0);
    }

    float mx[4] = {-3e38f, -3e38f, -3e38f, -3e38f};
#pragma unroll
    for (int mt = 0; mt < 13; ++mt) {
      const int m = mt * 16 + l15;
#pragma unroll
      for (int r = 0; r < 4; ++r) {
        const int n = n0 + g4 * 4 + r;
        float v = (m < 196 && n < 196) ? s[mt][r] + rv[mt][r] : -1e30f;
        s[mt][r] = v;
        mx[r] = fmaxf(mx[r], v);
      }
    }
#pragma unroll
    for (int r = 0; r < 4; ++r) {
      mx[r] = fmaxf(mx[r], __shfl_xor(mx[r], 1));
      mx[r] = fmaxf(mx[r], __shfl_xor(mx[r], 2));
      mx[r] = fmaxf(mx[r], __shfl_xor(mx[r], 4));
      mx[r] = fmaxf(mx[r], __shfl_xor(mx[r], 8));
    }
    float sm[4] = {0.f, 0.f, 0.f, 0.f};
#pragma unroll
    for (int mt = 0; mt < 13; ++mt)
#pragma unroll
      for (int r = 0; r < 4; ++r) {
        float p = __expf(s[mt][r] - mx[r]);
        s[mt][r] = p;
        sm[r] += p;
      }
#pragma unroll
    for (int r = 0; r < 4; ++r) {
      sm[r] += __shfl_xor(sm[r], 1);
      sm[r] += __shfl_xor(sm[r], 2);
      sm[r] += __shfl_xor(sm[r], 4);
      sm[r] += __shfl_xor(sm[r], 8);
    }
    float rinv[4];
#pragma unroll
    for (int r = 0; r < 4; ++r) rinv[r] = 1.f / sm[r];

#pragma unroll
    for (int mt = 0; mt < 13; ++mt) {
      const int m = mt * 16 + l15;
#pragma unroll
      for (int r = 0; r < 4; ++r) {
        const int n = g4 * 4 + r;
        f16* dst = (f16*)Pw + n * 256 + (((m >> 3) ^ (n & 7)) << 3) + (m & 7);
        *dst = (f16)s[mt][r];
      }
    }

    f32x4 o[4];
#pragma unroll
    for (int dt = 0; dt < 4; ++dt) o[dt] = zero4;
#pragma unroll
    for (int ks = 0; ks < 7; ++ks) {
      f16x8 pa = Pw[l15 * 32 + ((ks * 4 + g4) ^ (l15 & 7))];
#pragma unroll
      for (int dt = 0; dt < 4; ++dt) {
        const int d = dt * 16 + l15;
        f16x8 vf = Vlds[d * 32 + ((ks * 4 + g4) ^ (d & 7))];
        o[dt] = MFMA16(pa, vf, o[dt], 0, 0, 0);
      }
    }

#pragma unroll
    for (int r = 0; r < 4; ++r) {
      const int n = n0 + g4 * 4 + r;
      if (n < 196) {
        f16* orow = og + ((size_t)b * 196 + n) * 768 + h * 64;
#pragma unroll
        for (int dt = 0; dt < 4; ++dt)
          orow[dt * 16 + l15] = (f16)(o[dt][r] * rinv[r]);
      }
    }
  }
}

// ------------------------------- launcher ---------------------------------------
extern "C" void kernel_launch(void* const* d_in, const int* in_sizes, int n_in,
                              void* d_out, int out_size, void* d_ws, size_t ws_size,
                              hipStream_t stream) {
  const float* x = (const float*)d_in[0];
  const float* qkv_w = (const float*)d_in[1];
  const float* q_bias = (const float*)d_in[2];
  const float* v_bias = (const float*)d_in[3];
  const float* rpb_tab = (const float*)d_in[4];
  const float* proj_w = (const float*)d_in[5];
  const float* proj_b = (const float*)d_in[6];
  const int* rel = (const int*)d_in[7];
  float* out = (float*)d_out;

  const size_t SZ_Q = 77070336;   // [3072][196][64] f16
  const size_t SZ_K = 77070336;
  const size_t SZ_VT = 88080384;  // [3072][64][224] f16
  const size_t SZ_AO = 77070336;  // [50176][768] f16 (also hosts xh before attn)
  const size_t SZ_RP = 921984;    // [12][196][196] f16
  const size_t SZ_WQ = 3538944;   // [2304][768] f16
  const size_t SZ_WP = 1179648;   // [768][768] f16
  if (ws_size < SZ_Q + SZ_K + SZ_VT + SZ_AO + SZ_RP + SZ_WQ + SZ_WP) return;

  char* w = (char*)d_ws;
  f16* q_ = (f16*)w;
  f16* k_ = (f16*)(w + SZ_Q);
  f16* vT_ = (f16*)(w + SZ_Q + SZ_K);
  f16* ao_ = (f16*)(w + SZ_Q + SZ_K + SZ_VT);
  f16* rp_ = (f16*)(w + SZ_Q + SZ_K + SZ_VT + SZ_AO);
  f16* whq_ = (f16*)(w + SZ_Q + SZ_K + SZ_VT + SZ_AO + SZ_RP);
  f16* whp_ = (f16*)(w + SZ_Q + SZ_K + SZ_VT + SZ_AO + SZ_RP + SZ_WQ);
  f16* xh_ = ao_;  // alias: xh dead before attn writes ao_

  (void)hipFuncSetAttribute((const void*)attn_k,
                            hipFuncAttributeMaxDynamicSharedMemorySize, 65536);
  (void)hipFuncSetAttribute((const void*)gemm_k<0>,
                            hipFuncAttributeMaxDynamicSharedMemorySize, 163840);
  (void)hipFuncSetAttribute((const void*)gemm_k<1>,
                            hipFuncAttributeMaxDynamicSharedMemorySize, 163840);

  cvt_k<<<2048, 256, 0, stream>>>(x, xh_, 50176 * 768 / 8);
  cvt_k<<<864, 256, 0, stream>>>(qkv_w, whq_, 2304 * 768 / 8);
  cvt_k<<<288, 256, 0, stream>>>(proj_w, whp_, 768 * 768 / 8);
  rpb_build_k<<<(196 * 196 + 255) / 256, 256, 0, stream>>>(rpb_tab, rel, rp_);

  gemm_k<0><<<1764, 512, 163840, stream>>>(xh_, whq_, q_bias, v_bias,
                                           q_, k_, vT_, nullptr);
  attn_k<<<3072, 256, 65536, stream>>>(q_, k_, vT_, rp_, ao_);
  gemm_k<1><<<588, 512, 163840, stream>>>(ao_, whp_, proj_b, nullptr,
                                          nullptr, nullptr, nullptr, out);
}